// Round 3
// baseline (11771.706 us; speedup 1.0000x reference)
//
#include <hip/hip_runtime.h>
#include <cstdint>
#include <cstddef>

// Round 2: footprint 378MB -> ~105MB (bf16 intermediates + time-chunked zx).
// Evidence: rounds 0-2 all report absmax==8.5 == "d_out all zeros" == stub
// behavior => the ws_size guard fired. Adds a ws_size-encoding debug write on
// the guard path so a too-small ws is observable next round.

typedef unsigned short bf_t;
#define DEVI __device__ __forceinline__

DEVI float sigf(float x){ return 1.0f/(1.0f + expf(-x)); }
DEVI float bf2f(bf_t u){ return __uint_as_float(((unsigned)u)<<16); }
DEVI bf_t  f2bf(float f){ unsigned u=__float_as_uint(f); return (bf_t)((u + 0x7FFFu + ((u>>16)&1u))>>16); }

__global__ void k_dbg(float* out, unsigned mb){ out[0] = (float)mb; }

// ===== weight prep: gate-interleaved layouts =====
__global__ __launch_bounds__(256) void k_prep_char(const float* __restrict__ wcf,
    const float* __restrict__ wcb, float* __restrict__ wcg){
  int i = blockIdx.x*256 + threadIdx.x;
  if (i >= 2*150*100*4) return;
  int g = i & 3; int r = i >> 2;
  int u = r % 100; int r2 = r / 100;
  int k = r2 % 150; int dir = r2 / 150;
  const float* w = dir ? wcb : wcf;
  wcg[i] = w[k*400 + g*100 + u];
}
__global__ __launch_bounds__(256) void k_prep_word(const float* __restrict__ wwf,
    const float* __restrict__ wwb, float* __restrict__ wwg){
  int i = blockIdx.x*256 + threadIdx.x;
  if (i >= 2*512*512*4) return;
  int g = i & 3; int r = i >> 2;
  int c = r & 511; r >>= 9;
  int k = r & 511; int dir = r >> 9;
  const float* w = dir ? wwb : wwf;
  wwg[i] = w[(size_t)(500 + k)*2048 + g*512 + c];
}
__global__ __launch_bounds__(256) void k_prep_top(const float* __restrict__ wo,
    float* __restrict__ wog){
  int i = blockIdx.x*256 + threadIdx.x;
  if (i >= 512*512*4) return;
  int g = i & 3; int r = i >> 2;
  int c = r & 511; int k = r >> 9;
  wog[i] = wo[(size_t)(1024 + k)*2048 + g*512 + c];
}
// backward-direction row gather: ridxb[b*256+t] = b*256 + (t<L ? L-1-t : t)
__global__ __launch_bounds__(256) void k_ridx(const int* __restrict__ lens,
    int* __restrict__ ridxb){
  int b = blockIdx.x, t = threadIdx.x;
  int L = lens[b];
  int tin = (t < L) ? (L - 1 - t) : t;
  ridxb[b*256 + t] = b*256 + tin;
}

// ===== char BiLSTM: only final hidden states (rep bf16) =====
__global__ __launch_bounds__(256) void k_char(const float* __restrict__ subwords,
    const int* __restrict__ slens, const float* __restrict__ wcg,
    const float* __restrict__ bcf, const float* __restrict__ bcb,
    bf_t* __restrict__ rep){
  const int dir = blockIdx.y;
  const int s0 = blockIdx.x * 16;
  const int tid = threadIdx.x;
  __shared__ float xh[150][20];
  __shared__ int lens[16];

  if (tid < 16) lens[tid] = slens[s0 + tid];
  for (int i = tid; i < 100*16; i += 256) xh[50 + (i >> 4)][i & 15] = 0.0f;
  for (int i = tid; i < 800; i += 256) {
    int m = i / 50, k = i - m*50;
    int s = s0 + m;
    int te = dir ? (slens[s] - 1) : 0;
    xh[k][m] = subwords[((size_t)s*25 + te)*50 + k];
  }
  __syncthreads();

  const int u = tid & 127;
  const int grp = tid >> 7;
  const bool act = (u < 100);
  float b4[4] = {0.f,0.f,0.f,0.f};
  if (act) {
    const float* bc = dir ? bcb : bcf;
#pragma unroll
    for (int g = 0; g < 4; g++) b4[g] = bc[g*100 + u];
  }
  float c8[8];
#pragma unroll
  for (int m = 0; m < 8; m++) c8[m] = 0.0f;
  int lmax = 0;
#pragma unroll
  for (int m = 0; m < 8; m++) { int L = lens[grp*8 + m]; lmax = L > lmax ? L : lmax; }

  const float* wbase = wcg + (size_t)dir*150*100*4 + u*4;

  for (int t = 0; t < 25; t++) {
    float a[8][4];
#pragma unroll
    for (int m = 0; m < 8; m++)
#pragma unroll
      for (int g = 0; g < 4; g++) a[m][g] = 0.0f;
    if (act && t < lmax) {
      for (int k = 0; k < 150; k++) {
        float4 w = *(const float4*)(wbase + (size_t)k*400);
        float4 x0 = *(const float4*)&xh[k][grp*8];
        float4 x1 = *(const float4*)&xh[k][grp*8 + 4];
        float xv[8] = {x0.x,x0.y,x0.z,x0.w,x1.x,x1.y,x1.z,x1.w};
#pragma unroll
        for (int m = 0; m < 8; m++) {
          a[m][0] += xv[m]*w.x; a[m][1] += xv[m]*w.y;
          a[m][2] += xv[m]*w.z; a[m][3] += xv[m]*w.w;
        }
      }
    }
    __syncthreads();
    if (act) {
#pragma unroll
      for (int m = 0; m < 8; m++) {
        int s = grp*8 + m;
        int L = lens[s];
        if (t < L) {
          float zi = a[m][0] + b4[0];
          float zj = a[m][1] + b4[1];
          float zf = a[m][2] + b4[2];
          float zo = a[m][3] + b4[3];
          float cn = c8[m]*sigf(zf + 1.0f) + sigf(zi)*tanhf(zj);
          float hn = tanhf(cn)*sigf(zo);
          c8[m] = cn;
          xh[50 + u][s] = hn;
          if (t == L - 1) rep[(size_t)(s0 + s)*200 + dir*100 + u] = f2bf(hn);
        }
      }
    }
    if (t < 24) {
      for (int i = tid; i < 800; i += 256) {
        int m = i / 50, k = i - m*50;
        int s = s0 + m;
        int L = lens[m];
        int te = dir ? (L - 2 - t) : (t + 1);
        if (te < 0) te = 0;
        xh[k][m] = subwords[((size_t)s*25 + te)*50 + k];
      }
    }
    __syncthreads();
  }
}

// ===== word_in gather (bf16): [b,t] -> [tokens(300) | rep[tsub](200)] =====
__global__ __launch_bounds__(128) void k_win(const float* __restrict__ tokens,
    const bf_t* __restrict__ rep, const int* __restrict__ tsub,
    bf_t* __restrict__ win){
  int row = blockIdx.x;
  int idx = tsub[row];
  const float* tsrc = tokens + (size_t)row*300;
  const bf_t* rsrc = rep + (size_t)idx*200;
  bf_t* w = win + (size_t)row*500;
  for (int i = threadIdx.x; i < 500; i += 128)
    w[i] = (i < 300) ? f2bf(tsrc[i]) : rsrc[i - 300];
}

// ===== GEMM: C = gather(A)[M,K]@W[K,N] + bias. A bf16; W,bias f32.
// GATE=1: C bf16 gate-interleaved chunk [lr][c<512][g<4]; GATE=0: C f32 plain.
// t0>=0: virtual row v = (lr>>6)*256 + t0 + (lr&63) (time-chunked); else v=lr.
// z=blockIdx.z selects {W,bias,C,ridx}; ridx (if set) gathers A rows.
template<int GATE>
__global__ __launch_bounds__(256) void k_gemm(const bf_t* __restrict__ A, int lda, int K,
    const float* __restrict__ W0, const float* __restrict__ W1, int ldw,
    const float* __restrict__ b0, const float* __restrict__ b1,
    void* C0v, void* C1v, int ldc,
    const int* __restrict__ ridx1, int t0){
  const int z = blockIdx.z;
  const float* W = z ? W1 : W0;
  const float* bias = z ? b1 : b0;
  void* Cv = z ? C1v : C0v;
  const int* ridx = z ? ridx1 : nullptr;
  const int nb = blockIdx.x*64, rb = blockIdx.y*128;
  const int tid = threadIdx.x;
  const int tr = tid >> 4, tc = tid & 15;
  __shared__ float As[16][132];
  __shared__ float Bs[16][68];
  float acc[8][4];
#pragma unroll
  for (int i = 0; i < 8; i++)
#pragma unroll
    for (int j = 0; j < 4; j++) acc[i][j] = 0.f;
  const int ar = tid >> 1, ak = (tid & 1)*8;
  const int bk = tid >> 4, bn = (tid & 15)*4;
  // resolve this thread's staging row once
  int lr = rb + ar;
  int v = (t0 >= 0) ? ((lr >> 6)*256 + t0 + (lr & 63)) : lr;
  int ga = ridx ? ridx[v] : v;
  const bf_t* arow = A + (size_t)ga*lda;
  for (int kb = 0; kb < K; kb += 16) {
#pragma unroll
    for (int j = 0; j < 8; j++)
      As[ak + j][ar] = (kb + ak + j < K) ? bf2f(arow[kb + ak + j]) : 0.f;
    if (kb + bk < K) {
      const float* wp = W + (size_t)(kb + bk)*ldw + nb + bn;
      Bs[bk][bn] = wp[0]; Bs[bk][bn+1] = wp[1]; Bs[bk][bn+2] = wp[2]; Bs[bk][bn+3] = wp[3];
    } else {
      Bs[bk][bn] = 0.f; Bs[bk][bn+1] = 0.f; Bs[bk][bn+2] = 0.f; Bs[bk][bn+3] = 0.f;
    }
    __syncthreads();
#pragma unroll
    for (int kk = 0; kk < 16; kk++) {
      float4 a0 = *(const float4*)&As[kk][tr*8];
      float4 a1 = *(const float4*)&As[kk][tr*8 + 4];
      float4 bq = *(const float4*)&Bs[kk][tc*4];
      float av[8] = {a0.x,a0.y,a0.z,a0.w,a1.x,a1.y,a1.z,a1.w};
      float bv[4] = {bq.x,bq.y,bq.z,bq.w};
#pragma unroll
      for (int i = 0; i < 8; i++)
#pragma unroll
        for (int j = 0; j < 4; j++) acc[i][j] += av[i]*bv[j];
    }
    __syncthreads();
  }
  float4 bb = *(const float4*)&bias[nb + tc*4];
  float bias4[4] = {bb.x, bb.y, bb.z, bb.w};
#pragma unroll
  for (int i = 0; i < 8; i++) {
    int row = rb + tr*8 + i;
#pragma unroll
    for (int j = 0; j < 4; j++) {
      float vv = acc[i][j] + bias4[j];
      int n = nb + tc*4 + j;
      if (GATE) {
        ((bf_t*)Cv)[(size_t)row*2048 + (n & 511)*4 + (n >> 9)] = f2bf(vv);
      } else {
        int vr = (t0 >= 0) ? ((row >> 6)*256 + t0 + (row & 63)) : row;
        ((float*)Cv)[(size_t)vr*ldc + n] = vv;
      }
    }
  }
}

// ===== word BiLSTM one step (double-buffered h, chunked zx). grid 512, block 512 =====
__global__ __launch_bounds__(512) void k_word_step(const bf_t* __restrict__ zxf,
    const bf_t* __restrict__ zxb, const float* __restrict__ wwg,
    const int* __restrict__ seq_lens, const float* __restrict__ hr,
    float* __restrict__ hw, float* __restrict__ cst,
    bf_t* __restrict__ hid, int t){
  const int blk = blockIdx.x;
  const int dir = blk >> 8, rowg = (blk >> 6) & 3, colg = blk & 63;
  const int tid = threadIdx.x;
  const int kh = tid >> 7, r = (tid >> 3) & 15, c = tid & 7;
  __shared__ float hs[16][520];
  __shared__ float zp[3][16][8][4];
  const float* hsrc = hr + ((size_t)dir*64 + rowg*16)*512;
  for (int i = tid; i < 2048; i += 512) {
    int rr = i >> 7, kc = (i & 127) << 2;
    float4 v = *(const float4*)(hsrc + rr*512 + kc);
    hs[rr][kc] = v.x; hs[rr][kc+1] = v.y; hs[rr][kc+2] = v.z; hs[rr][kc+3] = v.w;
  }
  __syncthreads();
  const int b = rowg*16 + r, hcol = colg*8 + c;
  const int len = seq_lens[b];
  const bool active = (t < len);
  float ai = 0.f, aj = 0.f, af = 0.f, ao = 0.f;
  if (active) {
    const float* wp = wwg + ((size_t)dir*512*512 + hcol)*4 + (size_t)kh*128*2048;
#pragma unroll 4
    for (int k = 0; k < 128; k++) {
      float h = hs[r][kh*128 + k];
      float4 w = *(const float4*)(wp + (size_t)k*2048);
      ai += h*w.x; aj += h*w.y; af += h*w.z; ao += h*w.w;
    }
    if (kh) { zp[kh-1][r][c][0]=ai; zp[kh-1][r][c][1]=aj; zp[kh-1][r][c][2]=af; zp[kh-1][r][c][3]=ao; }
  }
  __syncthreads();
  if (kh == 0) {
    size_t sidx = ((size_t)dir*64 + b)*512 + hcol;
    float hout = hs[r][hcol];
    if (active) {
#pragma unroll
      for (int q = 0; q < 3; q++) {
        ai += zp[q][r][c][0]; aj += zp[q][r][c][1]; af += zp[q][r][c][2]; ao += zp[q][r][c][3];
      }
      const int tl = t & 63;
      const ushort4 zu = *(const ushort4*)((dir ? zxb : zxf) + ((size_t)(b*64 + tl))*2048 + hcol*4);
      float zx0 = bf2f(zu.x), zx1 = bf2f(zu.y), zx2 = bf2f(zu.z), zx3 = bf2f(zu.w);
      float cn = cst[sidx]*sigf(zx2 + af + 1.0f) + sigf(zx0 + ai)*tanhf(zx1 + aj);
      float hn = tanhf(cn)*sigf(zx3 + ao);
      cst[sidx] = cn;
      const int tin = dir ? (len - 1 - t) : t;
      hid[((size_t)b*256 + tin)*1024 + dir*512 + hcol] = f2bf(hn);
      hout = hn;
    }
    hw[sidx] = hout;
  }
}

// ===== top LSTM one step (double-buffered h, chunked zx). grid 256, block 512 =====
__global__ __launch_bounds__(512) void k_top_step(const bf_t* __restrict__ zxt,
    const float* __restrict__ wog, const int* __restrict__ seq_lens,
    const float* __restrict__ hr, float* __restrict__ hw, float* __restrict__ cst,
    bf_t* __restrict__ out2, int t){
  const int blk = blockIdx.x;
  const int rowg = (blk >> 6) & 3, colg = blk & 63;
  const int tid = threadIdx.x;
  const int kh = tid >> 7, r = (tid >> 3) & 15, c = tid & 7;
  __shared__ float hs[16][520];
  __shared__ float zp[3][16][8][4];
  const float* hsrc = hr + (size_t)rowg*16*512;
  for (int i = tid; i < 2048; i += 512) {
    int rr = i >> 7, kc = (i & 127) << 2;
    float4 v = *(const float4*)(hsrc + rr*512 + kc);
    hs[rr][kc] = v.x; hs[rr][kc+1] = v.y; hs[rr][kc+2] = v.z; hs[rr][kc+3] = v.w;
  }
  __syncthreads();
  const int b = rowg*16 + r, hcol = colg*8 + c;
  const int len = seq_lens[b];
  const bool active = (t < len);
  float ai = 0.f, aj = 0.f, af = 0.f, ao = 0.f;
  if (active) {
    const float* wp = wog + (size_t)hcol*4 + (size_t)kh*128*2048;
#pragma unroll 4
    for (int k = 0; k < 128; k++) {
      float h = hs[r][kh*128 + k];
      float4 w = *(const float4*)(wp + (size_t)k*2048);
      ai += h*w.x; aj += h*w.y; af += h*w.z; ao += h*w.w;
    }
    if (kh) { zp[kh-1][r][c][0]=ai; zp[kh-1][r][c][1]=aj; zp[kh-1][r][c][2]=af; zp[kh-1][r][c][3]=ao; }
  }
  __syncthreads();
  if (kh == 0) {
    size_t sidx = (size_t)b*512 + hcol;
    float hout = hs[r][hcol];
    if (active) {
#pragma unroll
      for (int q = 0; q < 3; q++) {
        ai += zp[q][r][c][0]; aj += zp[q][r][c][1]; af += zp[q][r][c][2]; ao += zp[q][r][c][3];
      }
      const int tl = t & 63;
      const ushort4 zu = *(const ushort4*)(zxt + ((size_t)(b*64 + tl))*2048 + hcol*4);
      float zx0 = bf2f(zu.x), zx1 = bf2f(zu.y), zx2 = bf2f(zu.z), zx3 = bf2f(zu.w);
      float cn = cst[sidx]*sigf(zx2 + af + 1.0f) + sigf(zx0 + ai)*tanhf(zx1 + aj);
      float hn = tanhf(cn)*sigf(zx3 + ao);
      cst[sidx] = cn;
      out2[((size_t)b*256 + t)*512 + hcol] = f2bf(hn);
      hout = hn;
    }
    hw[sidx] = hout;
  }
}

// ===== BN stats =====
__global__ __launch_bounds__(512) void k_bnstats(const bf_t* __restrict__ out2,
    float* __restrict__ gsum, float* __restrict__ gsq){
  int c = threadIdx.x;
  int r0 = blockIdx.x*256;
  float s = 0.f, q = 0.f;
  for (int i = 0; i < 256; i++) {
    float v = bf2f(out2[(size_t)(r0 + i)*512 + c]);
    s += v; q += v*v;
  }
  atomicAdd(&gsum[c], s);
  atomicAdd(&gsq[c], q);
}

// ===== fold BN into tag affine =====
__global__ __launch_bounds__(512) void k_bnfin(const float* __restrict__ gsum,
    const float* __restrict__ gsq, const float* __restrict__ gamma,
    const float* __restrict__ beta, const float* __restrict__ wt,
    const float* __restrict__ bt, float* __restrict__ wtp, float* __restrict__ btp){
  __shared__ float a_s[512], d_s[512];
  int c = threadIdx.x;
  float mean = gsum[c] * (1.0f/16384.0f);
  float var  = gsq[c]  * (1.0f/16384.0f) - mean*mean;
  float a = gamma[c] * rsqrtf(var + 1e-3f);
  a_s[c] = a;
  d_s[c] = beta[c] - mean*a;
  __syncthreads();
  for (int i = c; i < 512*64; i += 512) wtp[i] = a_s[i >> 6] * wt[i];
  if (c < 64) {
    float acc = bt[c];
    for (int cc = 0; cc < 512; cc++) acc += d_s[cc] * wt[cc*64 + c];
    btp[c] = acc;
  }
}

extern "C" void kernel_launch(void* const* d_in, const int* in_sizes, int n_in,
                              void* d_out, int out_size, void* d_ws, size_t ws_size,
                              hipStream_t stream) {
  const float* subwords = (const float*)d_in[0];
  const float* tokens   = (const float*)d_in[1];
  const int*   tsub     = (const int*)d_in[2];
  const int*   sublens  = (const int*)d_in[3];
  const int*   seqlens  = (const int*)d_in[4];
  const float* wcf = (const float*)d_in[5];
  const float* bcf = (const float*)d_in[6];
  const float* wcb = (const float*)d_in[7];
  const float* bcb = (const float*)d_in[8];
  const float* wwf = (const float*)d_in[9];
  const float* bwf = (const float*)d_in[10];
  const float* wwb = (const float*)d_in[11];
  const float* bwb = (const float*)d_in[12];
  const float* wo  = (const float*)d_in[13];
  const float* bo  = (const float*)d_in[14];
  const float* gma = (const float*)d_in[15];
  const float* bta = (const float*)d_in[16];
  const float* wt  = (const float*)d_in[17];
  const float* btb = (const float*)d_in[18];
  float* out = (float*)d_out;

  char* ws = (char*)d_ws;
  size_t off = 0;
  auto alc = [&](size_t bytes) -> void* {
    void* p = ws + off;
    off += (bytes + 255) & ~(size_t)255;
    return p;
  };
  bf_t* REP   = (bf_t*)alc(16384ull*200*2);     // 6.6 MB
  bf_t* WIN   = (bf_t*)alc(16384ull*500*2);     // 16.4 MB
  int*  RIDXB = (int*) alc(16384ull*4);
  bf_t* ZXF   = (bf_t*)alc(4096ull*2048*2);     // 16.8 MB chunk (also zx_top)
  bf_t* ZXB   = (bf_t*)alc(4096ull*2048*2);     // 16.8 MB chunk (also out2)
  bf_t* HID   = (bf_t*)alc(16384ull*1024*2);    // 33.6 MB
  const size_t STATF = 2*65536 + 65536 + 2*32768 + 32768 + 1024;
  float* STAT = (float*)alc(STATF*4);           // 1.2 MB
  float* HSTW0 = STAT;
  float* HSTW1 = HSTW0 + 65536;
  float* CSTW  = HSTW1 + 65536;
  float* HSTT0 = CSTW + 65536;
  float* HSTT1 = HSTT0 + 32768;
  float* CSTT  = HSTT1 + 32768;
  float* GSUM  = CSTT + 32768;
  float* GSQ   = GSUM + 512;
  float* WTP  = (float*)alc(512ull*64*4);
  float* BTP  = (float*)alc(64*4);
  float* WCG  = (float*)alc(2ull*150*100*4*4);  // 0.5 MB
  float* WWG  = (float*)alc(2ull*512*512*4*4);  // 8.4 MB
  float* WOG  = (float*)alc(512ull*512*4*4);    // 4.2 MB
  bf_t* ZXT  = ZXF;
  bf_t* OUT2 = ZXB;
  if (off > ws_size) {           // debug: encode ws_size (MB) into out[0]
    k_dbg<<<1, 1, 0, stream>>>(out, (unsigned)(ws_size >> 20));
    return;
  }

  hipMemsetAsync(HID, 0, 16384ull*1024*2, stream);
  hipMemsetAsync(STAT, 0, STATF*4, stream);

  k_prep_char<<<1875, 256, 0, stream>>>(wcf, wcb, WCG);
  k_prep_word<<<8192, 256, 0, stream>>>(wwf, wwb, WWG);
  k_prep_top<<<4096, 256, 0, stream>>>(wo, WOG);
  k_ridx<<<64, 256, 0, stream>>>(seqlens, RIDXB);

  k_char<<<dim3(1024, 2), 256, 0, stream>>>(subwords, sublens, WCG, bcf, bcb, REP);
  k_win<<<16384, 128, 0, stream>>>(tokens, REP, tsub, WIN);

  // word BiLSTM: 4 time-chunks of 64 steps; fwd(z=0) direct rows, bwd(z=1) gathered
  for (int ch = 0; ch < 4; ch++) {
    k_gemm<1><<<dim3(32, 32, 2), 256, 0, stream>>>(WIN, 500, 500, wwf, wwb, 2048,
                                                   bwf, bwb, ZXF, ZXB, 2048,
                                                   RIDXB, ch*64);
    for (int t = ch*64; t < ch*64 + 64; t++) {
      float* hr = (t & 1) ? HSTW1 : HSTW0;
      float* hw = (t & 1) ? HSTW0 : HSTW1;
      k_word_step<<<512, 512, 0, stream>>>(ZXF, ZXB, WWG, seqlens, hr, hw, CSTW, HID, t);
    }
  }

  hipMemsetAsync(OUT2, 0, 16384ull*512*2, stream);
  // top LSTM: 4 time-chunks
  for (int ch = 0; ch < 4; ch++) {
    k_gemm<1><<<dim3(32, 32, 1), 256, 0, stream>>>(HID, 1024, 1024, wo, nullptr, 2048,
                                                   bo, nullptr, ZXT, nullptr, 2048,
                                                   nullptr, ch*64);
    for (int t = ch*64; t < ch*64 + 64; t++) {
      float* hr = (t & 1) ? HSTT1 : HSTT0;
      float* hw = (t & 1) ? HSTT0 : HSTT1;
      k_top_step<<<256, 512, 0, stream>>>(ZXT, WOG, seqlens, hr, hw, CSTT, OUT2, t);
    }
  }

  k_bnstats<<<64, 512, 0, stream>>>(OUT2, GSUM, GSQ);
  k_bnfin<<<1, 512, 0, stream>>>(GSUM, GSQ, gma, bta, wt, btb, WTP, BTP);
  k_gemm<0><<<dim3(1, 128, 1), 256, 0, stream>>>(OUT2, 512, 512, WTP, nullptr, 64,
                                                 BTP, nullptr, out, nullptr, 64,
                                                 nullptr, -1);
}

// Round 4
// 9977.515 us; speedup vs baseline: 1.1798x; 1.1798x over previous
//
#include <hip/hip_runtime.h>
#include <cstdint>
#include <cstddef>

// Round 3: bf16 MFMA GEMMs for word-zx / top-zx (was f32 SIMT, ~6-8ms -> ~0.5ms
// predicted). Weights pre-transposed + column-permuted (n' = c*4+g) to bf16 so
// gate-interleaved zx layout is free. Recurrent step weights -> bf16 (halves L2
// traffic per step). Char LSTM + step kernels otherwise unchanged.

typedef unsigned short bf_t;
typedef __attribute__((ext_vector_type(8))) short bf16x8;
typedef __attribute__((ext_vector_type(4))) float f32x4;

#define DEVI __device__ __forceinline__
DEVI float sigf(float x){ return 1.0f/(1.0f + expf(-x)); }
DEVI float bf2f(bf_t u){ return __uint_as_float(((unsigned)u)<<16); }
DEVI bf_t  f2bf(float f){ unsigned u=__float_as_uint(f); return (bf_t)((u + 0x7FFFu + ((u>>16)&1u))>>16); }

__global__ void k_dbg(float* out, unsigned mb){ out[0] = (float)mb; }

// ===== weight prep =====
// char weights: f32 gate-interleaved [dir][k<150][u<100][g<4]
__global__ __launch_bounds__(256) void k_prep_char(const float* __restrict__ wcf,
    const float* __restrict__ wcb, float* __restrict__ wcg){
  int i = blockIdx.x*256 + threadIdx.x;
  if (i >= 2*150*100*4) return;
  int g = i & 3; int r = i >> 2;
  int u = r % 100; int r2 = r / 100;
  int k = r2 % 150; int dir = r2 / 150;
  const float* w = dir ? wcb : wcf;
  wcg[i] = w[k*400 + g*100 + u];
}
// word recurrent: bf16 gate-interleaved [dir][k<512][c<512][g<4]
__global__ __launch_bounds__(256) void k_prep_wrec(const float* __restrict__ wwf,
    const float* __restrict__ wwb, bf_t* __restrict__ wwg){
  int i = blockIdx.x*256 + threadIdx.x;
  if (i >= 2*512*512*4) return;
  int g = i & 3; int r = i >> 2;
  int c = r & 511; r >>= 9;
  int k = r & 511; int dir = r >> 9;
  const float* w = dir ? wwb : wwf;
  wwg[i] = f2bf(w[(size_t)(500 + k)*2048 + g*512 + c]);
}
// top recurrent: bf16 [k<512][c<512][g<4]
__global__ __launch_bounds__(256) void k_prep_trec(const float* __restrict__ wo,
    bf_t* __restrict__ wog){
  int i = blockIdx.x*256 + threadIdx.x;
  if (i >= 512*512*4) return;
  int g = i & 3; int r = i >> 2;
  int c = r & 511; int k = r >> 9;
  wog[i] = f2bf(wo[(size_t)(1024 + k)*2048 + g*512 + c]);
}
// word x-part, transposed + col-permuted bf16: wx[dir][np<2048][k<512], np=c*4+g
__global__ __launch_bounds__(256) void k_prep_wx(const float* __restrict__ wwf,
    const float* __restrict__ wwb, bf_t* __restrict__ wx){
  int i = blockIdx.x*256 + threadIdx.x;
  if (i >= 2*2048*512) return;
  int k = i & 511; int r = i >> 9;
  int np = r & 2047; int dir = r >> 11;
  int c = np >> 2, g = np & 3;
  const float* w = dir ? wwb : wwf;
  wx[i] = (k < 500) ? f2bf(w[(size_t)k*2048 + g*512 + c]) : (bf_t)0;
}
// top x-part: wxt[np<2048][k<1024]
__global__ __launch_bounds__(256) void k_prep_wxt(const float* __restrict__ wo,
    bf_t* __restrict__ wxt){
  int i = blockIdx.x*256 + threadIdx.x;
  if (i >= 2048*1024) return;
  int k = i & 1023; int np = i >> 10;
  int c = np >> 2, g = np & 3;
  wxt[i] = f2bf(wo[(size_t)k*2048 + g*512 + c]);
}
// permuted biases (np = c*4+g)
__global__ __launch_bounds__(256) void k_prep_bias(const float* __restrict__ bwf,
    const float* __restrict__ bwb, const float* __restrict__ bo,
    float* __restrict__ bpf, float* __restrict__ bpb, float* __restrict__ bpt){
  int np = blockIdx.x*256 + threadIdx.x;
  if (np >= 2048) return;
  int c = np >> 2, g = np & 3;
  bpf[np] = bwf[g*512 + c];
  bpb[np] = bwb[g*512 + c];
  bpt[np] = bo[g*512 + c];
}
// backward row gather: ridxb[b*256+t] = b*256 + (t<L ? L-1-t : t)
__global__ __launch_bounds__(256) void k_ridx(const int* __restrict__ lens,
    int* __restrict__ ridxb){
  int b = blockIdx.x, t = threadIdx.x;
  int L = lens[b];
  int tin = (t < L) ? (L - 1 - t) : t;
  ridxb[b*256 + t] = b*256 + tin;
}

// ===== char BiLSTM: only final hidden states (rep bf16) =====
__global__ __launch_bounds__(256) void k_char(const float* __restrict__ subwords,
    const int* __restrict__ slens, const float* __restrict__ wcg,
    const float* __restrict__ bcf, const float* __restrict__ bcb,
    bf_t* __restrict__ rep){
  const int dir = blockIdx.y;
  const int s0 = blockIdx.x * 16;
  const int tid = threadIdx.x;
  __shared__ float xh[150][20];
  __shared__ int lens[16];

  if (tid < 16) lens[tid] = slens[s0 + tid];
  for (int i = tid; i < 100*16; i += 256) xh[50 + (i >> 4)][i & 15] = 0.0f;
  for (int i = tid; i < 800; i += 256) {
    int m = i / 50, k = i - m*50;
    int s = s0 + m;
    int te = dir ? (slens[s] - 1) : 0;
    xh[k][m] = subwords[((size_t)s*25 + te)*50 + k];
  }
  __syncthreads();

  const int u = tid & 127;
  const int grp = tid >> 7;
  const bool act = (u < 100);
  float b4[4] = {0.f,0.f,0.f,0.f};
  if (act) {
    const float* bc = dir ? bcb : bcf;
#pragma unroll
    for (int g = 0; g < 4; g++) b4[g] = bc[g*100 + u];
  }
  float c8[8];
#pragma unroll
  for (int m = 0; m < 8; m++) c8[m] = 0.0f;
  int lmax = 0;
#pragma unroll
  for (int m = 0; m < 8; m++) { int L = lens[grp*8 + m]; lmax = L > lmax ? L : lmax; }

  const float* wbase = wcg + (size_t)dir*150*100*4 + u*4;

  for (int t = 0; t < 25; t++) {
    float a[8][4];
#pragma unroll
    for (int m = 0; m < 8; m++)
#pragma unroll
      for (int g = 0; g < 4; g++) a[m][g] = 0.0f;
    if (act && t < lmax) {
      for (int k = 0; k < 150; k++) {
        float4 w = *(const float4*)(wbase + (size_t)k*400);
        float4 x0 = *(const float4*)&xh[k][grp*8];
        float4 x1 = *(const float4*)&xh[k][grp*8 + 4];
        float xv[8] = {x0.x,x0.y,x0.z,x0.w,x1.x,x1.y,x1.z,x1.w};
#pragma unroll
        for (int m = 0; m < 8; m++) {
          a[m][0] += xv[m]*w.x; a[m][1] += xv[m]*w.y;
          a[m][2] += xv[m]*w.z; a[m][3] += xv[m]*w.w;
        }
      }
    }
    __syncthreads();
    if (act) {
#pragma unroll
      for (int m = 0; m < 8; m++) {
        int s = grp*8 + m;
        int L = lens[s];
        if (t < L) {
          float zi = a[m][0] + b4[0];
          float zj = a[m][1] + b4[1];
          float zf = a[m][2] + b4[2];
          float zo = a[m][3] + b4[3];
          float cn = c8[m]*sigf(zf + 1.0f) + sigf(zi)*tanhf(zj);
          float hn = tanhf(cn)*sigf(zo);
          c8[m] = cn;
          xh[50 + u][s] = hn;
          if (t == L - 1) rep[(size_t)(s0 + s)*200 + dir*100 + u] = f2bf(hn);
        }
      }
    }
    if (t < 24) {
      for (int i = tid; i < 800; i += 256) {
        int m = i / 50, k = i - m*50;
        int s = s0 + m;
        int L = lens[m];
        int te = dir ? (L - 2 - t) : (t + 1);
        if (te < 0) te = 0;
        xh[k][m] = subwords[((size_t)s*25 + te)*50 + k];
      }
    }
    __syncthreads();
  }
}

// ===== word_in gather (bf16, lda 512 zero-padded) =====
__global__ __launch_bounds__(128) void k_win(const float* __restrict__ tokens,
    const bf_t* __restrict__ rep, const int* __restrict__ tsub,
    bf_t* __restrict__ win){
  int row = blockIdx.x;
  int idx = tsub[row];
  const float* tsrc = tokens + (size_t)row*300;
  const bf_t* rsrc = rep + (size_t)idx*200;
  bf_t* w = win + (size_t)row*512;
  for (int i = threadIdx.x; i < 512; i += 128)
    w[i] = (i < 300) ? f2bf(tsrc[i]) : (i < 500 ? rsrc[i - 300] : (bf_t)0);
}

// ===== MFMA bf16 GEMM: C_chunk[4096][2048] = gather(A)[.,K] @ B[2048][K]^T + bias
// B pre-transposed ([n][k]) and col-permuted; C bf16 chunk-local rows.
// Tile 128x128, BK=32, 256 thr = 4 waves (2x2), 16x16x32 MFMA, frag-ordered LDS.
__global__ __launch_bounds__(256) void k_mgemm(const bf_t* __restrict__ A, int lda, int K,
    const bf_t* __restrict__ B0, const bf_t* __restrict__ B1,
    const float* __restrict__ bp0, const float* __restrict__ bp1,
    bf_t* __restrict__ C0, bf_t* __restrict__ C1,
    const int* __restrict__ ridx1, int t0){
  const int z = blockIdx.z;
  const bf_t* B = z ? B1 : B0;
  const float* bp = z ? bp1 : bp0;
  bf_t* C = z ? C1 : C0;
  const int* ridx = z ? ridx1 : nullptr;
  __shared__ short As[4096];  // 8KB; 16B slot s: row=(s>>6)*16+(s&15), koct=(s>>4)&3
  __shared__ short Bs[4096];
  const int tid = threadIdx.x;
  const int rb = blockIdx.y*128, nb = blockIdx.x*128;
  const bf_t* srcA[2]; const bf_t* srcB[2];
#pragma unroll
  for (int q = 0; q < 2; q++) {
    int s = tid + q*256;
    int row = ((s >> 6) << 4) + (s & 15), kg = (s >> 4) & 3;
    int lr = rb + row;
    int v = (t0 >= 0) ? ((lr >> 6)*256 + t0 + (lr & 63)) : lr;
    int ga = ridx ? ridx[v] : v;
    srcA[q] = A + (size_t)ga*lda + kg*8;
    srcB[q] = B + (size_t)(nb + row)*K + kg*8;
  }
  f32x4 acc[4][4];
#pragma unroll
  for (int i = 0; i < 4; i++)
#pragma unroll
    for (int j = 0; j < 4; j++) acc[i][j] = (f32x4){0.f,0.f,0.f,0.f};
  const int wid = tid >> 6, lane = tid & 63;
  const int wr = wid >> 1, wc = wid & 1;
  const int l16 = lane & 15, lk = lane >> 4;

  uint4 va0 = *(const uint4*)(srcA[0]);
  uint4 va1 = *(const uint4*)(srcA[1]);
  uint4 vb0 = *(const uint4*)(srcB[0]);
  uint4 vb1 = *(const uint4*)(srcB[1]);
  for (int kb = 0; kb < K; kb += 32) {
    __syncthreads();               // prior compute done before overwrite
    *(uint4*)&As[(size_t)tid*8] = va0;
    *(uint4*)&As[(size_t)(tid+256)*8] = va1;
    *(uint4*)&Bs[(size_t)tid*8] = vb0;
    *(uint4*)&Bs[(size_t)(tid+256)*8] = vb1;
    __syncthreads();
    if (kb + 32 < K) {             // prefetch next k-tile while MFMAs run
      va0 = *(const uint4*)(srcA[0] + kb + 32);
      va1 = *(const uint4*)(srcA[1] + kb + 32);
      vb0 = *(const uint4*)(srcB[0] + kb + 32);
      vb1 = *(const uint4*)(srcB[1] + kb + 32);
    }
    bf16x8 af[4], bfr[4];
#pragma unroll
    for (int f = 0; f < 4; f++) {
      af[f]  = *(const bf16x8*)&As[(((wr*4 + f)*4 + lk)*16 + l16)*8];
      bfr[f] = *(const bf16x8*)&Bs[(((wc*4 + f)*4 + lk)*16 + l16)*8];
    }
#pragma unroll
    for (int i = 0; i < 4; i++)
#pragma unroll
      for (int j = 0; j < 4; j++)
        acc[i][j] = __builtin_amdgcn_mfma_f32_16x16x32_bf16(af[i], bfr[j], acc[i][j], 0, 0, 0);
  }
#pragma unroll
  for (int i = 0; i < 4; i++) {
    int row0 = wr*64 + i*16 + lk*4;
#pragma unroll
    for (int j = 0; j < 4; j++) {
      int col = nb + wc*64 + j*16 + l16;
      float bv = bp[col];
#pragma unroll
      for (int r = 0; r < 4; r++)
        C[(size_t)(rb + row0 + r)*2048 + col] = f2bf(acc[i][j][r] + bv);
    }
  }
}

// ===== SIMT f32-acc GEMM for the small tag affine (A bf16, W/bias f32, C f32) =====
__global__ __launch_bounds__(256) void k_gemm_tag(const bf_t* __restrict__ A, int lda, int K,
    const float* __restrict__ W, int ldw, const float* __restrict__ bias,
    float* __restrict__ C, int ldc){
  const int nb = blockIdx.x*64, rb = blockIdx.y*128;
  const int tid = threadIdx.x;
  const int tr = tid >> 4, tc = tid & 15;
  __shared__ float As[16][132];
  __shared__ float Bs[16][68];
  float acc[8][4];
#pragma unroll
  for (int i = 0; i < 8; i++)
#pragma unroll
    for (int j = 0; j < 4; j++) acc[i][j] = 0.f;
  const int ar = tid >> 1, ak = (tid & 1)*8;
  const int bk = tid >> 4, bn = (tid & 15)*4;
  const bf_t* arow = A + (size_t)(rb + ar)*lda;
  for (int kb = 0; kb < K; kb += 16) {
#pragma unroll
    for (int j = 0; j < 8; j++)
      As[ak + j][ar] = bf2f(arow[kb + ak + j]);
    const float* wp = W + (size_t)(kb + bk)*ldw + nb + bn;
    Bs[bk][bn] = wp[0]; Bs[bk][bn+1] = wp[1]; Bs[bk][bn+2] = wp[2]; Bs[bk][bn+3] = wp[3];
    __syncthreads();
#pragma unroll
    for (int kk = 0; kk < 16; kk++) {
      float4 a0 = *(const float4*)&As[kk][tr*8];
      float4 a1 = *(const float4*)&As[kk][tr*8 + 4];
      float4 bq = *(const float4*)&Bs[kk][tc*4];
      float av[8] = {a0.x,a0.y,a0.z,a0.w,a1.x,a1.y,a1.z,a1.w};
      float bv[4] = {bq.x,bq.y,bq.z,bq.w};
#pragma unroll
      for (int i = 0; i < 8; i++)
#pragma unroll
        for (int j = 0; j < 4; j++) acc[i][j] += av[i]*bv[j];
    }
    __syncthreads();
  }
  float4 bb = *(const float4*)&bias[nb + tc*4];
  float bias4[4] = {bb.x, bb.y, bb.z, bb.w};
#pragma unroll
  for (int i = 0; i < 8; i++) {
    size_t row = rb + tr*8 + i;
#pragma unroll
    for (int j = 0; j < 4; j++)
      C[row*(size_t)ldc + nb + tc*4 + j] = acc[i][j] + bias4[j];
  }
}

// ===== word BiLSTM one step (bf16 weights, double-buffered h). grid 512, block 512 =====
__global__ __launch_bounds__(512) void k_word_step(const bf_t* __restrict__ zxf,
    const bf_t* __restrict__ zxb, const bf_t* __restrict__ wwg,
    const int* __restrict__ seq_lens, const float* __restrict__ hr,
    float* __restrict__ hw, float* __restrict__ cst,
    bf_t* __restrict__ hid, int t){
  const int blk = blockIdx.x;
  const int dir = blk >> 8, rowg = (blk >> 6) & 3, colg = blk & 63;
  const int tid = threadIdx.x;
  const int kh = tid >> 7, r = (tid >> 3) & 15, c = tid & 7;
  __shared__ float hs[16][520];
  __shared__ float zp[3][16][8][4];
  const float* hsrc = hr + ((size_t)dir*64 + rowg*16)*512;
  for (int i = tid; i < 2048; i += 512) {
    int rr = i >> 7, kc = (i & 127) << 2;
    float4 v = *(const float4*)(hsrc + rr*512 + kc);
    hs[rr][kc] = v.x; hs[rr][kc+1] = v.y; hs[rr][kc+2] = v.z; hs[rr][kc+3] = v.w;
  }
  __syncthreads();
  const int b = rowg*16 + r, hcol = colg*8 + c;
  const int len = seq_lens[b];
  const bool active = (t < len);
  float ai = 0.f, aj = 0.f, af = 0.f, ao = 0.f;
  if (active) {
    const bf_t* wp = wwg + ((size_t)dir*512*512 + hcol)*4 + (size_t)kh*128*2048;
#pragma unroll 4
    for (int k = 0; k < 128; k++) {
      float h = hs[r][kh*128 + k];
      ushort4 w4 = *(const ushort4*)(wp + (size_t)k*2048);
      ai += h*bf2f(w4.x); aj += h*bf2f(w4.y); af += h*bf2f(w4.z); ao += h*bf2f(w4.w);
    }
    if (kh) { zp[kh-1][r][c][0]=ai; zp[kh-1][r][c][1]=aj; zp[kh-1][r][c][2]=af; zp[kh-1][r][c][3]=ao; }
  }
  __syncthreads();
  if (kh == 0) {
    size_t sidx = ((size_t)dir*64 + b)*512 + hcol;
    float hout = hs[r][hcol];
    if (active) {
#pragma unroll
      for (int q = 0; q < 3; q++) {
        ai += zp[q][r][c][0]; aj += zp[q][r][c][1]; af += zp[q][r][c][2]; ao += zp[q][r][c][3];
      }
      const int tl = t & 63;
      const ushort4 zu = *(const ushort4*)((dir ? zxb : zxf) + ((size_t)(b*64 + tl))*2048 + hcol*4);
      float cn = cst[sidx]*sigf(bf2f(zu.z) + af + 1.0f) + sigf(bf2f(zu.x) + ai)*tanhf(bf2f(zu.y) + aj);
      float hn = tanhf(cn)*sigf(bf2f(zu.w) + ao);
      cst[sidx] = cn;
      const int tin = dir ? (len - 1 - t) : t;
      hid[((size_t)b*256 + tin)*1024 + dir*512 + hcol] = f2bf(hn);
      hout = hn;
    }
    hw[sidx] = hout;
  }
}

// ===== top LSTM one step (bf16 weights). grid 256, block 512 =====
__global__ __launch_bounds__(512) void k_top_step(const bf_t* __restrict__ zxt,
    const bf_t* __restrict__ wog, const int* __restrict__ seq_lens,
    const float* __restrict__ hr, float* __restrict__ hw, float* __restrict__ cst,
    bf_t* __restrict__ out2, int t){
  const int blk = blockIdx.x;
  const int rowg = (blk >> 6) & 3, colg = blk & 63;
  const int tid = threadIdx.x;
  const int kh = tid >> 7, r = (tid >> 3) & 15, c = tid & 7;
  __shared__ float hs[16][520];
  __shared__ float zp[3][16][8][4];
  const float* hsrc = hr + (size_t)rowg*16*512;
  for (int i = tid; i < 2048; i += 512) {
    int rr = i >> 7, kc = (i & 127) << 2;
    float4 v = *(const float4*)(hsrc + rr*512 + kc);
    hs[rr][kc] = v.x; hs[rr][kc+1] = v.y; hs[rr][kc+2] = v.z; hs[rr][kc+3] = v.w;
  }
  __syncthreads();
  const int b = rowg*16 + r, hcol = colg*8 + c;
  const int len = seq_lens[b];
  const bool active = (t < len);
  float ai = 0.f, aj = 0.f, af = 0.f, ao = 0.f;
  if (active) {
    const bf_t* wp = wog + (size_t)hcol*4 + (size_t)kh*128*2048;
#pragma unroll 4
    for (int k = 0; k < 128; k++) {
      float h = hs[r][kh*128 + k];
      ushort4 w4 = *(const ushort4*)(wp + (size_t)k*2048);
      ai += h*bf2f(w4.x); aj += h*bf2f(w4.y); af += h*bf2f(w4.z); ao += h*bf2f(w4.w);
    }
    if (kh) { zp[kh-1][r][c][0]=ai; zp[kh-1][r][c][1]=aj; zp[kh-1][r][c][2]=af; zp[kh-1][r][c][3]=ao; }
  }
  __syncthreads();
  if (kh == 0) {
    size_t sidx = (size_t)b*512 + hcol;
    float hout = hs[r][hcol];
    if (active) {
#pragma unroll
      for (int q = 0; q < 3; q++) {
        ai += zp[q][r][c][0]; aj += zp[q][r][c][1]; af += zp[q][r][c][2]; ao += zp[q][r][c][3];
      }
      const int tl = t & 63;
      const ushort4 zu = *(const ushort4*)(zxt + ((size_t)(b*64 + tl))*2048 + hcol*4);
      float cn = cst[sidx]*sigf(bf2f(zu.z) + af + 1.0f) + sigf(bf2f(zu.x) + ai)*tanhf(bf2f(zu.y) + aj);
      float hn = tanhf(cn)*sigf(bf2f(zu.w) + ao);
      cst[sidx] = cn;
      out2[((size_t)b*256 + t)*512 + hcol] = f2bf(hn);
      hout = hn;
    }
    hw[sidx] = hout;
  }
}

// ===== BN stats =====
__global__ __launch_bounds__(512) void k_bnstats(const bf_t* __restrict__ out2,
    float* __restrict__ gsum, float* __restrict__ gsq){
  int c = threadIdx.x;
  int r0 = blockIdx.x*256;
  float s = 0.f, q = 0.f;
  for (int i = 0; i < 256; i++) {
    float v = bf2f(out2[(size_t)(r0 + i)*512 + c]);
    s += v; q += v*v;
  }
  atomicAdd(&gsum[c], s);
  atomicAdd(&gsq[c], q);
}

// ===== fold BN into tag affine =====
__global__ __launch_bounds__(512) void k_bnfin(const float* __restrict__ gsum,
    const float* __restrict__ gsq, const float* __restrict__ gamma,
    const float* __restrict__ beta, const float* __restrict__ wt,
    const float* __restrict__ bt, float* __restrict__ wtp, float* __restrict__ btp){
  __shared__ float a_s[512], d_s[512];
  int c = threadIdx.x;
  float mean = gsum[c] * (1.0f/16384.0f);
  float var  = gsq[c]  * (1.0f/16384.0f) - mean*mean;
  float a = gamma[c] * rsqrtf(var + 1e-3f);
  a_s[c] = a;
  d_s[c] = beta[c] - mean*a;
  __syncthreads();
  for (int i = c; i < 512*64; i += 512) wtp[i] = a_s[i >> 6] * wt[i];
  if (c < 64) {
    float acc = bt[c];
    for (int cc = 0; cc < 512; cc++) acc += d_s[cc] * wt[cc*64 + c];
    btp[c] = acc;
  }
}

extern "C" void kernel_launch(void* const* d_in, const int* in_sizes, int n_in,
                              void* d_out, int out_size, void* d_ws, size_t ws_size,
                              hipStream_t stream) {
  const float* subwords = (const float*)d_in[0];
  const float* tokens   = (const float*)d_in[1];
  const int*   tsub     = (const int*)d_in[2];
  const int*   sublens  = (const int*)d_in[3];
  const int*   seqlens  = (const int*)d_in[4];
  const float* wcf = (const float*)d_in[5];
  const float* bcf = (const float*)d_in[6];
  const float* wcb = (const float*)d_in[7];
  const float* bcb = (const float*)d_in[8];
  const float* wwf = (const float*)d_in[9];
  const float* bwf = (const float*)d_in[10];
  const float* wwb = (const float*)d_in[11];
  const float* bwb = (const float*)d_in[12];
  const float* wo  = (const float*)d_in[13];
  const float* bo  = (const float*)d_in[14];
  const float* gma = (const float*)d_in[15];
  const float* bta = (const float*)d_in[16];
  const float* wt  = (const float*)d_in[17];
  const float* btb = (const float*)d_in[18];
  float* out = (float*)d_out;

  char* ws = (char*)d_ws;
  size_t off = 0;
  auto alc = [&](size_t bytes) -> void* {
    void* p = ws + off;
    off += (bytes + 255) & ~(size_t)255;
    return p;
  };
  bf_t* REP   = (bf_t*)alc(16384ull*200*2);     // 6.6 MB
  bf_t* WIN   = (bf_t*)alc(16384ull*512*2);     // 16.8 MB (lda 512, zero-padded)
  int*  RIDXB = (int*) alc(16384ull*4);
  bf_t* ZXF   = (bf_t*)alc(4096ull*2048*2);     // chunk (also zx_top)
  bf_t* ZXB   = (bf_t*)alc(4096ull*2048*2);     // chunk (also out2)
  bf_t* HID   = (bf_t*)alc(16384ull*1024*2);    // 33.6 MB
  const size_t STATF = 2*65536 + 65536 + 2*32768 + 32768 + 1024;
  float* STAT = (float*)alc(STATF*4);
  float* HSTW0 = STAT;
  float* HSTW1 = HSTW0 + 65536;
  float* CSTW  = HSTW1 + 65536;
  float* HSTT0 = CSTW + 65536;
  float* HSTT1 = HSTT0 + 32768;
  float* CSTT  = HSTT1 + 32768;
  float* GSUM  = CSTT + 32768;
  float* GSQ   = GSUM + 512;
  float* WTP  = (float*)alc(512ull*64*4);
  float* BTP  = (float*)alc(64*4);
  float* WCG  = (float*)alc(2ull*150*100*4*4);  // char weights f32
  bf_t* WWG  = (bf_t*)alc(2ull*512*512*4*2);    // word recurrent bf16
  bf_t* WOG  = (bf_t*)alc(512ull*512*4*2);      // top recurrent bf16
  bf_t* WXG  = (bf_t*)alc(2ull*2048*512*2);     // word x weights [dir][n'][k]
  bf_t* WXT  = (bf_t*)alc(2048ull*1024*2);      // top x weights [n'][k]
  float* BPF = (float*)alc(2048*4);
  float* BPB = (float*)alc(2048*4);
  float* BPT = (float*)alc(2048*4);
  bf_t* ZXT  = ZXF;
  bf_t* OUT2 = ZXB;
  if (off > ws_size) {           // debug: encode ws_size (MB) into out[0]
    k_dbg<<<1, 1, 0, stream>>>(out, (unsigned)(ws_size >> 20));
    return;
  }

  hipMemsetAsync(HID, 0, 16384ull*1024*2, stream);
  hipMemsetAsync(STAT, 0, STATF*4, stream);

  k_prep_char<<<1875, 256, 0, stream>>>(wcf, wcb, WCG);
  k_prep_wrec<<<8192, 256, 0, stream>>>(wwf, wwb, WWG);
  k_prep_trec<<<4096, 256, 0, stream>>>(wo, WOG);
  k_prep_wx<<<8192, 256, 0, stream>>>(wwf, wwb, WXG);
  k_prep_wxt<<<8192, 256, 0, stream>>>(wo, WXT);
  k_prep_bias<<<8, 256, 0, stream>>>(bwf, bwb, bo, BPF, BPB, BPT);
  k_ridx<<<64, 256, 0, stream>>>(seqlens, RIDXB);

  k_char<<<dim3(1024, 2), 256, 0, stream>>>(subwords, sublens, WCG, bcf, bcb, REP);
  k_win<<<16384, 128, 0, stream>>>(tokens, REP, tsub, WIN);

  // word BiLSTM: 4 time-chunks of 64 steps (MFMA zx GEMM per chunk)
  for (int ch = 0; ch < 4; ch++) {
    k_mgemm<<<dim3(16, 32, 2), 256, 0, stream>>>(WIN, 512, 512,
        WXG, WXG + 2048ull*512, BPF, BPB, ZXF, ZXB, RIDXB, ch*64);
    for (int t = ch*64; t < ch*64 + 64; t++) {
      float* hr = (t & 1) ? HSTW1 : HSTW0;
      float* hw = (t & 1) ? HSTW0 : HSTW1;
      k_word_step<<<512, 512, 0, stream>>>(ZXF, ZXB, WWG, seqlens, hr, hw, CSTW, HID, t);
    }
  }

  hipMemsetAsync(OUT2, 0, 16384ull*512*2, stream);
  // top LSTM: 4 time-chunks
  for (int ch = 0; ch < 4; ch++) {
    k_mgemm<<<dim3(16, 32, 1), 256, 0, stream>>>(HID, 1024, 1024,
        WXT, nullptr, BPT, nullptr, ZXT, nullptr, nullptr, ch*64);
    for (int t = ch*64; t < ch*64 + 64; t++) {
      float* hr = (t & 1) ? HSTT1 : HSTT0;
      float* hw = (t & 1) ? HSTT0 : HSTT1;
      k_top_step<<<256, 512, 0, stream>>>(ZXT, WOG, seqlens, hr, hw, CSTT, OUT2, t);
    }
  }

  k_bnstats<<<64, 512, 0, stream>>>(OUT2, GSUM, GSQ);
  k_bnfin<<<1, 512, 0, stream>>>(GSUM, GSQ, gma, bta, wt, btb, WTP, BTP);
  k_gemm_tag<<<dim3(1, 128, 1), 256, 0, stream>>>(OUT2, 512, 512, WTP, 64, BTP, out, 64);
}